// Round 3
// baseline (9020.779 us; speedup 1.0000x reference)
//
#include <hip/hip_runtime.h>
#include <hip/hip_bf16.h>
#include <cstddef>

#define B 256
#define S 128
#define H 512
#define G 2048

__device__ __forceinline__ float sigmoidf_(float x){ return 1.f/(1.f+expf(-x)); }

// ---------------- init: zero hA and c, y = future_init_outcome ----------------
__global__ void init_kernel(float* __restrict__ hA, float* __restrict__ c,
                            float* __restrict__ y, const float* __restrict__ fio){
  int i = blockIdx.x*blockDim.x + threadIdx.x;
  if (i < B*H){ hA[i] = 0.f; c[i] = 0.f; }
  if (i < B) y[i] = fio[i];
}

// ---------------- e_x = relu(temporal_x @ temp_W + temp_b) ----------------
__global__ __launch_bounds__(128) void embed_x_kernel(const float* __restrict__ tx,
    const float* __restrict__ W, const float* __restrict__ bvec, float* __restrict__ ex){
  __shared__ float xs[64];
  int bt = blockIdx.x, j = threadIdx.x;
  if (j < 64) xs[j] = tx[(size_t)bt*64 + j];
  __syncthreads();
  float a = bvec[j];
  #pragma unroll 8
  for (int k = 0; k < 64; ++k) a += xs[k]*W[k*128 + j];
  ex[(size_t)bt*128 + j] = fmaxf(a, 0.f);
}

// ---------------- e_d = relu(static_x @ stat_W + stat_b) ----------------
__global__ __launch_bounds__(128) void embed_d_kernel(const float* __restrict__ sx,
    const float* __restrict__ W, const float* __restrict__ bvec, float* __restrict__ ed){
  __shared__ float xs[32];
  int b = blockIdx.x, j = threadIdx.x;
  if (j < 32) xs[j] = sx[(size_t)b*32 + j];
  __syncthreads();
  float a = bvec[j];
  #pragma unroll 8
  for (int k = 0; k < 32; ++k) a += xs[k]*W[k*128 + j];
  ed[(size_t)b*128 + j] = fmaxf(a, 0.f);
}

// ---------------- encoder LSTM step (fused GEMM + gates) ----------------
// Tile: 32 b x 32 j (x4 gates). Grid (8,16). Reads hin (fp32, stride H),
// writes hout (fp32) + eo16 (bf16 history for attention).
__global__ __launch_bounds__(256) void enc_step_kernel(
    const float* ex, const float* ed, const float* hist,
    const float* Wih, const float* Whh, const float* bias,
    const float* hin, float* c, float* hout,
    __hip_bfloat16* eo16, int t)
{
  __shared__ float As[32][33];
  __shared__ __align__(16) float Bs[4][32][34];
  const int tid = threadIdx.x;
  const int tx = tid & 15, ty = tid >> 4;
  const int b0 = blockIdx.x * 32, j0 = blockIdx.y * 32;
  const int lr = tid >> 3, lk = (tid & 7) * 4;
  float acc[4][2][2] = {};

  for (int kt = 0; kt < 24; ++kt) {
    const float4* ap;
    const float* brow;
    if (kt < 4) {                       // k in [0,128): e_x part, Wih rows 0..127
      ap = (const float4*)&ex[((size_t)(b0+lr)*S + t)*128 + kt*32 + lk];
      brow = &Wih[(size_t)(kt*32 + lr)*G];
    } else if (kt < 8) {                // k in [128,256): e_d part, Wih rows 128..255
      ap = (const float4*)&ed[(size_t)(b0+lr)*128 + (kt-4)*32 + lk];
      brow = &Wih[(size_t)(128 + (kt-4)*32 + lr)*G];
    } else {                            // k in [0,512): h part, Whh
      ap = (const float4*)&hin[(size_t)(b0+lr)*H + (kt-8)*32 + lk];
      brow = &Whh[(size_t)((kt-8)*32 + lr)*G];
    }
    float4 av = *ap;
    float4 bv[4];
    #pragma unroll
    for (int g = 0; g < 4; ++g) bv[g] = *(const float4*)&brow[g*512 + j0 + lk];
    __syncthreads();
    As[lr][lk+0]=av.x; As[lr][lk+1]=av.y; As[lr][lk+2]=av.z; As[lr][lk+3]=av.w;
    #pragma unroll
    for (int g = 0; g < 4; ++g){
      Bs[g][lr][lk+0]=bv[g].x; Bs[g][lr][lk+1]=bv[g].y;
      Bs[g][lr][lk+2]=bv[g].z; Bs[g][lr][lk+3]=bv[g].w;
    }
    __syncthreads();
    #pragma unroll
    for (int kk = 0; kk < 32; ++kk){
      float a0 = As[ty*2+0][kk], a1 = As[ty*2+1][kk];
      #pragma unroll
      for (int g = 0; g < 4; ++g){
        float2 b2 = *(const float2*)&Bs[g][kk][tx*2];
        acc[g][0][0] += a0*b2.x; acc[g][0][1] += a0*b2.y;
        acc[g][1][0] += a1*b2.x; acc[g][1][1] += a1*b2.y;
      }
    }
  }

  #pragma unroll
  for (int db = 0; db < 2; ++db){
    int b_ = b0 + ty*2 + db;
    float hv = hist[(size_t)b_*S + t];
    #pragma unroll
    for (int dj = 0; dj < 2; ++dj){
      int j_ = j0 + tx*2 + dj;
      float gi = acc[0][db][dj] + bias[       j_] + hv*Wih[(size_t)256*G +        j_];
      float gf = acc[1][db][dj] + bias[ 512 + j_] + hv*Wih[(size_t)256*G +  512 + j_];
      float gg = acc[2][db][dj] + bias[1024 + j_] + hv*Wih[(size_t)256*G + 1024 + j_];
      float go = acc[3][db][dj] + bias[1536 + j_] + hv*Wih[(size_t)256*G + 1536 + j_];
      size_t ci = (size_t)b_*H + j_;
      float cn = sigmoidf_(gf)*c[ci] + sigmoidf_(gi)*tanhf(gg);
      float hn = sigmoidf_(go)*tanhf(cn);
      c[ci] = cn;
      hout[ci] = hn;
      eo16[((size_t)b_*S + t)*H + j_] = __float2bfloat16(hn);
    }
  }
}

// ---------------- decoder LSTM step ----------------
__global__ __launch_bounds__(256) void dec_step_kernel(
    const float* ed, const float* y, const float* fut,
    const float* Wih, const float* Whh, const float* bias,
    const float* hin, float* c, float* hout, int t)
{
  __shared__ float As[32][33];
  __shared__ __align__(16) float Bs[4][32][34];
  const int tid = threadIdx.x;
  const int tx = tid & 15, ty = tid >> 4;
  const int b0 = blockIdx.x * 32, j0 = blockIdx.y * 32;
  const int lr = tid >> 3, lk = (tid & 7) * 4;
  float acc[4][2][2] = {};

  for (int kt = 0; kt < 20; ++kt) {
    const float4* ap;
    const float* brow;
    if (kt < 4) {                       // k in [0,128): e_d part, Wih rows 0..127
      ap = (const float4*)&ed[(size_t)(b0+lr)*128 + kt*32 + lk];
      brow = &Wih[(size_t)(kt*32 + lr)*G];
    } else {                            // k in [0,512): h part, Whh
      ap = (const float4*)&hin[(size_t)(b0+lr)*H + (kt-4)*32 + lk];
      brow = &Whh[(size_t)((kt-4)*32 + lr)*G];
    }
    float4 av = *ap;
    float4 bv[4];
    #pragma unroll
    for (int g = 0; g < 4; ++g) bv[g] = *(const float4*)&brow[g*512 + j0 + lk];
    __syncthreads();
    As[lr][lk+0]=av.x; As[lr][lk+1]=av.y; As[lr][lk+2]=av.z; As[lr][lk+3]=av.w;
    #pragma unroll
    for (int g = 0; g < 4; ++g){
      Bs[g][lr][lk+0]=bv[g].x; Bs[g][lr][lk+1]=bv[g].y;
      Bs[g][lr][lk+2]=bv[g].z; Bs[g][lr][lk+3]=bv[g].w;
    }
    __syncthreads();
    #pragma unroll
    for (int kk = 0; kk < 32; ++kk){
      float a0 = As[ty*2+0][kk], a1 = As[ty*2+1][kk];
      #pragma unroll
      for (int g = 0; g < 4; ++g){
        float2 b2 = *(const float2*)&Bs[g][kk][tx*2];
        acc[g][0][0] += a0*b2.x; acc[g][0][1] += a0*b2.y;
        acc[g][1][0] += a1*b2.x; acc[g][1][1] += a1*b2.y;
      }
    }
  }

  #pragma unroll
  for (int db = 0; db < 2; ++db){
    int b_ = b0 + ty*2 + db;
    float yv = y[b_];
    float av_ = fut[(size_t)b_*16 + t];
    #pragma unroll
    for (int dj = 0; dj < 2; ++dj){
      int j_ = j0 + tx*2 + dj;
      float gi = acc[0][db][dj] + bias[       j_] + yv*Wih[(size_t)128*G +        j_] + av_*Wih[(size_t)129*G +        j_];
      float gf = acc[1][db][dj] + bias[ 512 + j_] + yv*Wih[(size_t)128*G +  512 + j_] + av_*Wih[(size_t)129*G +  512 + j_];
      float gg = acc[2][db][dj] + bias[1024 + j_] + yv*Wih[(size_t)128*G + 1024 + j_] + av_*Wih[(size_t)129*G + 1024 + j_];
      float go = acc[3][db][dj] + bias[1536 + j_] + yv*Wih[(size_t)128*G + 1536 + j_] + av_*Wih[(size_t)129*G + 1536 + j_];
      size_t ci = (size_t)b_*H + j_;
      float cn = sigmoidf_(gf)*c[ci] + sigmoidf_(gi)*tanhf(gg);
      float hn = sigmoidf_(go)*tanhf(cn);
      c[ci] = cn;
      hout[ci] = hn;
    }
  }
}

// ---------------- propensity logits + enc_We (one pass over eo16) ----------------
__global__ __launch_bounds__(256) void prop_we_kernel(
    const __hip_bfloat16* __restrict__ eo, const float* __restrict__ propW,
    const float* __restrict__ propb, const float* __restrict__ attnW,
    float* __restrict__ prop_out, float* __restrict__ encWe)
{
  int row = blockIdx.x*4 + (threadIdx.x >> 6);
  int lane = threadIdx.x & 63;
  const __hip_bfloat16* e = &eo[(size_t)row*H];
  float ap = 0.f, aw = 0.f;
  #pragma unroll
  for (int i = 0; i < 8; ++i){
    float v = __bfloat162float(e[lane + i*64]);
    ap += v*propW[lane + i*64];
    aw += v*attnW[512 + lane + i*64];
  }
  #pragma unroll
  for (int off = 32; off; off >>= 1){ ap += __shfl_down(ap, off); aw += __shfl_down(aw, off); }
  if (lane == 0){
    prop_out[row] = ap + propb[0];
    encWe[row] = aw;
  }
}

// ---------------- attention + context + prediction (per decoder step) ----------------
__global__ __launch_bounds__(256) void attn_pred_kernel(
    const __hip_bfloat16* __restrict__ eo, const float* __restrict__ encWe,
    const float* __restrict__ h,
    const float* __restrict__ attnW, const float* __restrict__ attnb,
    const float* __restrict__ outW, const float* __restrict__ outb,
    const float* __restrict__ fut,
    float* __restrict__ y, float* __restrict__ out, int t)
{
  int b = blockIdx.x, tid = threadIdx.x;
  __shared__ float hWi[512];
  __shared__ float red[256];
  __shared__ float sc[128];
  __shared__ float smax, ssum, shWh;

  float hv0 = h[(size_t)b*H + tid];
  float hv1 = h[(size_t)b*H + 256 + tid];
  hWi[tid]       = hv0 * attnW[1024 + tid];
  hWi[tid + 256] = hv1 * attnW[1024 + 256 + tid];
  red[tid] = hv0*attnW[tid] + hv1*attnW[256 + tid];
  __syncthreads();
  for (int off = 128; off; off >>= 1){
    if (tid < off) red[tid] += red[tid + off];
    __syncthreads();
  }
  if (tid == 0) shWh = red[0];
  __syncthreads();

  // scores: each of 4 waves handles 32 s values
  int lane = tid & 63;
  for (int s = (tid >> 6); s < S; s += 4){
    const __hip_bfloat16* e = &eo[((size_t)b*S + s)*H];
    float a = 0.f;
    #pragma unroll
    for (int i = 0; i < 8; ++i) a += __bfloat162float(e[lane + i*64])*hWi[lane + i*64];
    #pragma unroll
    for (int off = 32; off; off >>= 1) a += __shfl_down(a, off);
    if (lane == 0) sc[s] = tanhf(shWh + encWe[(size_t)b*S + s] + a + attnb[0]);
  }
  __syncthreads();

  // softmax over 128 scores
  if (tid < 64){
    float m = fmaxf(sc[tid], sc[tid + 64]);
    #pragma unroll
    for (int off = 32; off; off >>= 1) m = fmaxf(m, __shfl_down(m, off));
    if (tid == 0) smax = m;
  }
  __syncthreads();
  if (tid < 128){ float e = expf(sc[tid] - smax); sc[tid] = e; red[tid] = e; }
  else red[tid] = 0.f;
  __syncthreads();
  for (int off = 128; off; off >>= 1){
    if (tid < off) red[tid] += red[tid + off];
    __syncthreads();
  }
  if (tid == 0) ssum = red[0];
  __syncthreads();
  float inv = 1.f / ssum;

  // context dims tid and tid+256
  float c0 = 0.f, c1 = 0.f;
  for (int s = 0; s < S; ++s){
    float w = sc[s];
    const __hip_bfloat16* e = &eo[((size_t)b*S + s)*H];
    c0 += w*__bfloat162float(e[tid]);
    c1 += w*__bfloat162float(e[tid + 256]);
  }
  c0 *= inv; c1 *= inv;

  // pred = [h, context, a_t] @ out_W + out_b
  red[tid] = hv0*outW[tid] + hv1*outW[256 + tid] + c0*outW[512 + tid] + c1*outW[768 + tid];
  __syncthreads();
  for (int off = 128; off; off >>= 1){
    if (tid < off) red[tid] += red[tid + off];
    __syncthreads();
  }
  if (tid == 0){
    float at = fut[(size_t)b*16 + t];
    float p = red[0] + at*outW[1024] + outb[0];
    y[b] = p;
    out[(size_t)b*16 + t] = p;
  }
}

extern "C" void kernel_launch(void* const* d_in, const int* in_sizes, int n_in,
                              void* d_out, int out_size, void* d_ws, size_t ws_size,
                              hipStream_t stream)
{
  const float* temporal_x = (const float*)d_in[0];
  const float* static_x   = (const float*)d_in[1];
  const float* hist       = (const float*)d_in[2];
  const float* fut        = (const float*)d_in[3];
  const float* fio        = (const float*)d_in[4];
  const float* temp_W = (const float*)d_in[5];
  const float* temp_b = (const float*)d_in[6];
  const float* stat_W = (const float*)d_in[7];
  const float* stat_b = (const float*)d_in[8];
  const float* eWih = (const float*)d_in[9];
  const float* eWhh = (const float*)d_in[10];
  const float* eb   = (const float*)d_in[11];
  const float* attnW = (const float*)d_in[12];
  const float* attnb = (const float*)d_in[13];
  const float* dWih = (const float*)d_in[14];
  const float* dWhh = (const float*)d_in[15];
  const float* dbias = (const float*)d_in[16];
  const float* outW = (const float*)d_in[17];
  const float* outb = (const float*)d_in[18];
  const float* propW = (const float*)d_in[19];
  const float* propb = (const float*)d_in[20];
  float* out = (float*)d_out;   // fp32 output: [B*16 preds][B*S propensity]

  // workspace layout (floats) — total ~13.3M floats ≈ 53 MB
  float* ws = (float*)d_ws;
  float* ex    = ws;                          // B*S*128 = 4,194,304
  float* ed    = ex + (size_t)B*S*128;        // B*128   = 32,768
  float* hA    = ed + (size_t)B*128;          // B*H
  float* hB    = hA + (size_t)B*H;            // B*H
  float* cb    = hB + (size_t)B*H;            // B*H
  float* encWe = cb + (size_t)B*H;            // B*S
  float* yb    = encWe + (size_t)B*S;         // B
  float* dh0   = yb + B;                      // B*H
  float* dh1   = dh0 + (size_t)B*H;           // B*H
  __hip_bfloat16* eo16 = (__hip_bfloat16*)(dh1 + (size_t)B*H); // B*S*H bf16

  init_kernel<<<(B*H + 255)/256, 256, 0, stream>>>(hA, cb, yb, fio);
  embed_x_kernel<<<B*S, 128, 0, stream>>>(temporal_x, temp_W, temp_b, ex);
  embed_d_kernel<<<B, 128, 0, stream>>>(static_x, stat_W, stat_b, ed);

  // encoder: t even reads hA writes hB; t odd reads hB writes hA.
  // S=128 even -> final h_n lands in hA.
  for (int t = 0; t < S; ++t){
    const float* hin = (t & 1) ? hB : hA;
    float* hout      = (t & 1) ? hA : hB;
    enc_step_kernel<<<dim3(8,16), 256, 0, stream>>>(ex, ed, hist, eWih, eWhh, eb,
                                                    hin, cb, hout, eo16, t);
  }

  prop_we_kernel<<<(B*S)/4, 256, 0, stream>>>(eo16, propW, propb, attnW, out + B*16, encWe);

  for (int t = 0; t < 16; ++t){
    const float* hp = (t == 0) ? hA : ((t & 1) ? dh0 : dh1);
    float* ho = (t & 1) ? dh1 : dh0;
    dec_step_kernel<<<dim3(8,16), 256, 0, stream>>>(ed, yb, fut, dWih, dWhh, dbias,
                                                    hp, cb, ho, t);
    attn_pred_kernel<<<B, 256, 0, stream>>>(eo16, encWe, ho, attnW, attnb, outW, outb,
                                            fut, yb, out, t);
  }
}

// Round 4
// 4499.336 us; speedup vs baseline: 2.0049x; 2.0049x over previous
//
#include <hip/hip_runtime.h>
#include <hip/hip_bf16.h>
#include <cstddef>

#define B 256
#define S 128
#define H 512
#define G 2048

__device__ __forceinline__ float sigmoidf_(float x){ return 1.f/(1.f+expf(-x)); }

// ---------------- init: zero hA and c, y = future_init_outcome ----------------
__global__ void init_kernel(float* __restrict__ hA, float* __restrict__ c,
                            float* __restrict__ y, const float* __restrict__ fio){
  int i = blockIdx.x*blockDim.x + threadIdx.x;
  if (i < B*H){ hA[i] = 0.f; c[i] = 0.f; }
  if (i < B) y[i] = fio[i];
}

// ---------------- e_x = relu(temporal_x @ temp_W + temp_b) ----------------
__global__ __launch_bounds__(128) void embed_x_kernel(const float* __restrict__ tx,
    const float* __restrict__ W, const float* __restrict__ bvec, float* __restrict__ ex){
  __shared__ float xs[64];
  int bt = blockIdx.x, j = threadIdx.x;
  if (j < 64) xs[j] = tx[(size_t)bt*64 + j];
  __syncthreads();
  float a = bvec[j];
  #pragma unroll 8
  for (int k = 0; k < 64; ++k) a += xs[k]*W[k*128 + j];
  ex[(size_t)bt*128 + j] = fmaxf(a, 0.f);
}

// ---------------- e_d = relu(static_x @ stat_W + stat_b) ----------------
__global__ __launch_bounds__(128) void embed_d_kernel(const float* __restrict__ sx,
    const float* __restrict__ W, const float* __restrict__ bvec, float* __restrict__ ed){
  __shared__ float xs[32];
  int b = blockIdx.x, j = threadIdx.x;
  if (j < 32) xs[j] = sx[(size_t)b*32 + j];
  __syncthreads();
  float a = bvec[j];
  #pragma unroll 8
  for (int k = 0; k < 32; ++k) a += xs[k]*W[k*128 + j];
  ed[(size_t)b*128 + j] = fmaxf(a, 0.f);
}

// ---------------- gd = ed @ W[wrow0:wrow0+128] + bias  (B x 2048) ----------------
__global__ __launch_bounds__(256) void gd_kernel(const float* __restrict__ ed,
    const float* __restrict__ W, int wrow0, const float* __restrict__ bias,
    float* __restrict__ gd){
  __shared__ float eds[128];
  int b = blockIdx.x, tid = threadIdx.x;
  if (tid < 128) eds[tid] = ed[(size_t)b*128 + tid];
  __syncthreads();
  int n = blockIdx.y*256 + tid;
  float a = bias[n];
  #pragma unroll 8
  for (int k = 0; k < 128; ++k) a += eds[k]*W[(size_t)(wrow0 + k)*G + n];
  gd[(size_t)b*G + n] = a;
}

// ======== encoder step v2: g = gd + ex_t@Wih[0:128] + h@Whh, fused gates ========
// Tile 32b x 16j x 4gates, grid (8,32)=256 blocks, 256 threads, 8 acc/thread.
// LDS double-buffered, register prefetch, one barrier per 32-k chunk.
__global__ __launch_bounds__(256) void enc_step2(
    const float* __restrict__ ex, const float* __restrict__ hist,
    const float* __restrict__ Wih, const float* __restrict__ Whh,
    const float* __restrict__ gd,
    const float* __restrict__ hin, float* __restrict__ c,
    float* __restrict__ hout, __hip_bfloat16* __restrict__ eo16, int t)
{
  __shared__ float As[2][32][44];        // [buf][b][k] rows 16B-aligned, 2-way banks
  __shared__ float Bs[2][4][16][44];     // [buf][gate][j][k]
  const int tid = threadIdx.x;
  const int tx = tid & 15;               // j within tile
  const int ty = tid >> 4;               // b-pair 0..15
  const int b0 = blockIdx.x * 32;
  const int j0 = blockIdx.y * 16;
  const int lr = tid >> 3, lk = (tid & 7) * 4;   // A-stage: row, k
  const int li1 = tid + 256;
  // B-stage decode for li0=tid and li1
  const int kr0 = tid >> 4,  s0 = tid & 15,  g0 = s0 >> 2, f0 = (s0 & 3)*4;
  const int kr1 = li1 >> 4,  s1 = li1 & 15,  g1 = s1 >> 2, f1 = (s1 & 3)*4;

  float acc[4][2] = {};
  const int NC = 20;                     // 4 ex-chunks + 16 h-chunks

  // ---- prologue: stage chunk 0 (ex part) ----
  float4 av  = *(const float4*)&ex[((size_t)(b0+lr)*S + t)*128 + lk];
  float4 wv0 = *(const float4*)&Wih[(size_t)kr0*G + g0*512 + j0 + f0];
  float4 wv1 = *(const float4*)&Wih[(size_t)kr1*G + g1*512 + j0 + f1];
  *(float4*)&As[0][lr][lk] = av;
  Bs[0][g0][f0+0][kr0]=wv0.x; Bs[0][g0][f0+1][kr0]=wv0.y; Bs[0][g0][f0+2][kr0]=wv0.z; Bs[0][g0][f0+3][kr0]=wv0.w;
  Bs[0][g1][f1+0][kr1]=wv1.x; Bs[0][g1][f1+1][kr1]=wv1.y; Bs[0][g1][f1+2][kr1]=wv1.z; Bs[0][g1][f1+3][kr1]=wv1.w;
  __syncthreads();

  for (int ch = 0; ch < NC; ++ch){
    const int cur = ch & 1, nxt = cur ^ 1;
    const bool more = (ch+1 < NC);
    if (more){
      const int cn = ch + 1;
      if (cn < 4){
        av  = *(const float4*)&ex[((size_t)(b0+lr)*S + t)*128 + cn*32 + lk];
        wv0 = *(const float4*)&Wih[(size_t)(cn*32+kr0)*G + g0*512 + j0 + f0];
        wv1 = *(const float4*)&Wih[(size_t)(cn*32+kr1)*G + g1*512 + j0 + f1];
      } else {
        av  = *(const float4*)&hin[(size_t)(b0+lr)*H + (cn-4)*32 + lk];
        wv0 = *(const float4*)&Whh[(size_t)((cn-4)*32+kr0)*G + g0*512 + j0 + f0];
        wv1 = *(const float4*)&Whh[(size_t)((cn-4)*32+kr1)*G + g1*512 + j0 + f1];
      }
    }
    #pragma unroll
    for (int u = 0; u < 8; ++u){
      const int k0 = u*4;
      float4 a0 = *(const float4*)&As[cur][ty*2+0][k0];
      float4 a1 = *(const float4*)&As[cur][ty*2+1][k0];
      #pragma unroll
      for (int g = 0; g < 4; ++g){
        float4 w = *(const float4*)&Bs[cur][g][tx][k0];
        acc[g][0] += a0.x*w.x + a0.y*w.y + a0.z*w.z + a0.w*w.w;
        acc[g][1] += a1.x*w.x + a1.y*w.y + a1.z*w.z + a1.w*w.w;
      }
    }
    if (more){
      *(float4*)&As[nxt][lr][lk] = av;
      Bs[nxt][g0][f0+0][kr0]=wv0.x; Bs[nxt][g0][f0+1][kr0]=wv0.y; Bs[nxt][g0][f0+2][kr0]=wv0.z; Bs[nxt][g0][f0+3][kr0]=wv0.w;
      Bs[nxt][g1][f1+0][kr1]=wv1.x; Bs[nxt][g1][f1+1][kr1]=wv1.y; Bs[nxt][g1][f1+2][kr1]=wv1.z; Bs[nxt][g1][f1+3][kr1]=wv1.w;
    }
    __syncthreads();
  }

  // ---- epilogue: gates + c/h update ----
  const int j_ = j0 + tx;
  #pragma unroll
  for (int bp = 0; bp < 2; ++bp){
    const int b_ = b0 + ty*2 + bp;
    const float hv = hist[(size_t)b_*S + t];
    float gate[4];
    #pragma unroll
    for (int g = 0; g < 4; ++g){
      const int n = g*512 + j_;
      gate[g] = acc[g][bp] + gd[(size_t)b_*G + n] + hv*Wih[(size_t)256*G + n];
    }
    const size_t ci = (size_t)b_*H + j_;
    float cn = sigmoidf_(gate[1])*c[ci] + sigmoidf_(gate[0])*tanhf(gate[2]);
    float hn = sigmoidf_(gate[3])*tanhf(cn);
    c[ci] = cn;
    hout[ci] = hn;
    eo16[((size_t)b_*S + t)*H + j_] = __float2bfloat16(hn);
  }
}

// ======== decoder step v2: g = gdd + y*Wy + a*Wa + h@Whh ========
__global__ __launch_bounds__(256) void dec_step2(
    const float* __restrict__ y, const float* __restrict__ fut,
    const float* __restrict__ Wih, const float* __restrict__ Whh,
    const float* __restrict__ gdd,
    const float* __restrict__ hin, float* __restrict__ c,
    float* __restrict__ hout, int t)
{
  __shared__ float As[2][32][44];
  __shared__ float Bs[2][4][16][44];
  const int tid = threadIdx.x;
  const int tx = tid & 15;
  const int ty = tid >> 4;
  const int b0 = blockIdx.x * 32;
  const int j0 = blockIdx.y * 16;
  const int lr = tid >> 3, lk = (tid & 7) * 4;
  const int li1 = tid + 256;
  const int kr0 = tid >> 4,  s0 = tid & 15,  g0 = s0 >> 2, f0 = (s0 & 3)*4;
  const int kr1 = li1 >> 4,  s1 = li1 & 15,  g1 = s1 >> 2, f1 = (s1 & 3)*4;

  float acc[4][2] = {};
  const int NC = 16;                     // 16 h-chunks (K=512)

  float4 av  = *(const float4*)&hin[(size_t)(b0+lr)*H + lk];
  float4 wv0 = *(const float4*)&Whh[(size_t)kr0*G + g0*512 + j0 + f0];
  float4 wv1 = *(const float4*)&Whh[(size_t)kr1*G + g1*512 + j0 + f1];
  *(float4*)&As[0][lr][lk] = av;
  Bs[0][g0][f0+0][kr0]=wv0.x; Bs[0][g0][f0+1][kr0]=wv0.y; Bs[0][g0][f0+2][kr0]=wv0.z; Bs[0][g0][f0+3][kr0]=wv0.w;
  Bs[0][g1][f1+0][kr1]=wv1.x; Bs[0][g1][f1+1][kr1]=wv1.y; Bs[0][g1][f1+2][kr1]=wv1.z; Bs[0][g1][f1+3][kr1]=wv1.w;
  __syncthreads();

  for (int ch = 0; ch < NC; ++ch){
    const int cur = ch & 1, nxt = cur ^ 1;
    const bool more = (ch+1 < NC);
    if (more){
      const int cn = ch + 1;
      av  = *(const float4*)&hin[(size_t)(b0+lr)*H + cn*32 + lk];
      wv0 = *(const float4*)&Whh[(size_t)(cn*32+kr0)*G + g0*512 + j0 + f0];
      wv1 = *(const float4*)&Whh[(size_t)(cn*32+kr1)*G + g1*512 + j0 + f1];
    }
    #pragma unroll
    for (int u = 0; u < 8; ++u){
      const int k0 = u*4;
      float4 a0 = *(const float4*)&As[cur][ty*2+0][k0];
      float4 a1 = *(const float4*)&As[cur][ty*2+1][k0];
      #pragma unroll
      for (int g = 0; g < 4; ++g){
        float4 w = *(const float4*)&Bs[cur][g][tx][k0];
        acc[g][0] += a0.x*w.x + a0.y*w.y + a0.z*w.z + a0.w*w.w;
        acc[g][1] += a1.x*w.x + a1.y*w.y + a1.z*w.z + a1.w*w.w;
      }
    }
    if (more){
      *(float4*)&As[nxt][lr][lk] = av;
      Bs[nxt][g0][f0+0][kr0]=wv0.x; Bs[nxt][g0][f0+1][kr0]=wv0.y; Bs[nxt][g0][f0+2][kr0]=wv0.z; Bs[nxt][g0][f0+3][kr0]=wv0.w;
      Bs[nxt][g1][f1+0][kr1]=wv1.x; Bs[nxt][g1][f1+1][kr1]=wv1.y; Bs[nxt][g1][f1+2][kr1]=wv1.z; Bs[nxt][g1][f1+3][kr1]=wv1.w;
    }
    __syncthreads();
  }

  const int j_ = j0 + tx;
  #pragma unroll
  for (int bp = 0; bp < 2; ++bp){
    const int b_ = b0 + ty*2 + bp;
    const float yv  = y[b_];
    const float av_ = fut[(size_t)b_*16 + t];
    float gate[4];
    #pragma unroll
    for (int g = 0; g < 4; ++g){
      const int n = g*512 + j_;
      gate[g] = acc[g][bp] + gdd[(size_t)b_*G + n]
              + yv*Wih[(size_t)128*G + n] + av_*Wih[(size_t)129*G + n];
    }
    const size_t ci = (size_t)b_*H + j_;
    float cn = sigmoidf_(gate[1])*c[ci] + sigmoidf_(gate[0])*tanhf(gate[2]);
    float hn = sigmoidf_(gate[3])*tanhf(cn);
    c[ci] = cn;
    hout[ci] = hn;
  }
}

// ---------------- propensity logits + enc_We (one pass over eo16) ----------------
__global__ __launch_bounds__(256) void prop_we_kernel(
    const __hip_bfloat16* __restrict__ eo, const float* __restrict__ propW,
    const float* __restrict__ propb, const float* __restrict__ attnW,
    float* __restrict__ prop_out, float* __restrict__ encWe)
{
  int row = blockIdx.x*4 + (threadIdx.x >> 6);
  int lane = threadIdx.x & 63;
  const __hip_bfloat16* e = &eo[(size_t)row*H];
  float ap = 0.f, aw = 0.f;
  #pragma unroll
  for (int i = 0; i < 8; ++i){
    float v = __bfloat162float(e[lane + i*64]);
    ap += v*propW[lane + i*64];
    aw += v*attnW[512 + lane + i*64];
  }
  #pragma unroll
  for (int off = 32; off; off >>= 1){ ap += __shfl_down(ap, off); aw += __shfl_down(aw, off); }
  if (lane == 0){
    prop_out[row] = ap + propb[0];
    encWe[row] = aw;
  }
}

// ---------------- attention + context + prediction (per decoder step) ----------------
__global__ __launch_bounds__(256) void attn_pred_kernel(
    const __hip_bfloat16* __restrict__ eo, const float* __restrict__ encWe,
    const float* __restrict__ h,
    const float* __restrict__ attnW, const float* __restrict__ attnb,
    const float* __restrict__ outW, const float* __restrict__ outb,
    const float* __restrict__ fut,
    float* __restrict__ y, float* __restrict__ out, int t)
{
  int b = blockIdx.x, tid = threadIdx.x;
  __shared__ float hWi[512];
  __shared__ float red[256];
  __shared__ float sc[128];
  __shared__ float smax, ssum, shWh;

  float hv0 = h[(size_t)b*H + tid];
  float hv1 = h[(size_t)b*H + 256 + tid];
  hWi[tid]       = hv0 * attnW[1024 + tid];
  hWi[tid + 256] = hv1 * attnW[1024 + 256 + tid];
  red[tid] = hv0*attnW[tid] + hv1*attnW[256 + tid];
  __syncthreads();
  for (int off = 128; off; off >>= 1){
    if (tid < off) red[tid] += red[tid + off];
    __syncthreads();
  }
  if (tid == 0) shWh = red[0];
  __syncthreads();

  int lane = tid & 63;
  for (int s = (tid >> 6); s < S; s += 4){
    const __hip_bfloat16* e = &eo[((size_t)b*S + s)*H];
    float a = 0.f;
    #pragma unroll
    for (int i = 0; i < 8; ++i) a += __bfloat162float(e[lane + i*64])*hWi[lane + i*64];
    #pragma unroll
    for (int off = 32; off; off >>= 1) a += __shfl_down(a, off);
    if (lane == 0) sc[s] = tanhf(shWh + encWe[(size_t)b*S + s] + a + attnb[0]);
  }
  __syncthreads();

  if (tid < 64){
    float m = fmaxf(sc[tid], sc[tid + 64]);
    #pragma unroll
    for (int off = 32; off; off >>= 1) m = fmaxf(m, __shfl_down(m, off));
    if (tid == 0) smax = m;
  }
  __syncthreads();
  if (tid < 128){ float e = expf(sc[tid] - smax); sc[tid] = e; red[tid] = e; }
  else red[tid] = 0.f;
  __syncthreads();
  for (int off = 128; off; off >>= 1){
    if (tid < off) red[tid] += red[tid + off];
    __syncthreads();
  }
  if (tid == 0) ssum = red[0];
  __syncthreads();
  float inv = 1.f / ssum;

  float c0 = 0.f, c1 = 0.f;
  for (int s = 0; s < S; ++s){
    float w = sc[s];
    const __hip_bfloat16* e = &eo[((size_t)b*S + s)*H];
    c0 += w*__bfloat162float(e[tid]);
    c1 += w*__bfloat162float(e[tid + 256]);
  }
  c0 *= inv; c1 *= inv;

  red[tid] = hv0*outW[tid] + hv1*outW[256 + tid] + c0*outW[512 + tid] + c1*outW[768 + tid];
  __syncthreads();
  for (int off = 128; off; off >>= 1){
    if (tid < off) red[tid] += red[tid + off];
    __syncthreads();
  }
  if (tid == 0){
    float at = fut[(size_t)b*16 + t];
    float p = red[0] + at*outW[1024] + outb[0];
    y[b] = p;
    out[(size_t)b*16 + t] = p;
  }
}

extern "C" void kernel_launch(void* const* d_in, const int* in_sizes, int n_in,
                              void* d_out, int out_size, void* d_ws, size_t ws_size,
                              hipStream_t stream)
{
  const float* temporal_x = (const float*)d_in[0];
  const float* static_x   = (const float*)d_in[1];
  const float* hist       = (const float*)d_in[2];
  const float* fut        = (const float*)d_in[3];
  const float* fio        = (const float*)d_in[4];
  const float* temp_W = (const float*)d_in[5];
  const float* temp_b = (const float*)d_in[6];
  const float* stat_W = (const float*)d_in[7];
  const float* stat_b = (const float*)d_in[8];
  const float* eWih = (const float*)d_in[9];
  const float* eWhh = (const float*)d_in[10];
  const float* eb   = (const float*)d_in[11];
  const float* attnW = (const float*)d_in[12];
  const float* attnb = (const float*)d_in[13];
  const float* dWih = (const float*)d_in[14];
  const float* dWhh = (const float*)d_in[15];
  const float* dbias = (const float*)d_in[16];
  const float* outW = (const float*)d_in[17];
  const float* outb = (const float*)d_in[18];
  const float* propW = (const float*)d_in[19];
  const float* propb = (const float*)d_in[20];
  float* out = (float*)d_out;   // fp32: [B*16 preds][B*S propensity]

  // workspace layout (floats), ~54.3 MB total
  float* ws = (float*)d_ws;
  float* ex    = ws;                          // B*S*128 = 4,194,304
  float* ed    = ex + (size_t)B*S*128;        // B*128
  float* hA    = ed + (size_t)B*128;          // B*H
  float* hB    = hA + (size_t)B*H;            // B*H
  float* cb    = hB + (size_t)B*H;            // B*H
  float* encWe = cb + (size_t)B*H;            // B*S
  float* yb    = encWe + (size_t)B*S;         // B
  float* gd_e  = yb + B;                      // B*G = 524,288
  __hip_bfloat16* eo16 = (__hip_bfloat16*)(gd_e + (size_t)B*G); // B*S*H bf16
  // decoder-phase reuse of the (dead) ex region:
  float* gd_d  = ex;                          // B*G
  float* dh0   = ex + (size_t)B*G;            // B*H
  float* dh1   = dh0 + (size_t)B*H;           // B*H

  init_kernel<<<(B*H + 255)/256, 256, 0, stream>>>(hA, cb, yb, fio);
  embed_x_kernel<<<B*S, 128, 0, stream>>>(temporal_x, temp_W, temp_b, ex);
  embed_d_kernel<<<B, 128, 0, stream>>>(static_x, stat_W, stat_b, ed);
  gd_kernel<<<dim3(B,8), 256, 0, stream>>>(ed, eWih, 128, eb, gd_e);

  // encoder: even t reads hA writes hB; odd t reads hB writes hA. h_n ends in hA.
  for (int t = 0; t < S; ++t){
    const float* hin = (t & 1) ? hB : hA;
    float* hout      = (t & 1) ? hA : hB;
    enc_step2<<<dim3(8,32), 256, 0, stream>>>(ex, hist, eWih, eWhh, gd_e,
                                              hin, cb, hout, eo16, t);
  }

  // gd_d overwrites ex region — only after the encoder is done with ex.
  gd_kernel<<<dim3(B,8), 256, 0, stream>>>(ed, dWih, 0, dbias, gd_d);
  prop_we_kernel<<<(B*S)/4, 256, 0, stream>>>(eo16, propW, propb, attnW, out + B*16, encWe);

  for (int t = 0; t < 16; ++t){
    const float* hp = (t == 0) ? hA : ((t & 1) ? dh0 : dh1);
    float* ho = (t & 1) ? dh1 : dh0;
    dec_step2<<<dim3(8,32), 256, 0, stream>>>(yb, fut, dWih, dWhh, gd_d,
                                              hp, cb, ho, t);
    attn_pred_kernel<<<B, 256, 0, stream>>>(eo16, encWe, ho, attnW, attnb, outW, outb,
                                            fut, yb, out, t);
  }
}

// Round 5
// 4458.342 us; speedup vs baseline: 2.0233x; 1.0092x over previous
//
#include <hip/hip_runtime.h>
#include <hip/hip_bf16.h>
#include <cstddef>

#define B 256
#define S 128
#define H 512
#define G 2048

__device__ __forceinline__ float sigmoidf_(float x){ return 1.f/(1.f+expf(-x)); }

// ---------------- init: zero hA and c, y = future_init_outcome ----------------
__global__ void init_kernel(float* __restrict__ hA, float* __restrict__ c,
                            float* __restrict__ y, const float* __restrict__ fio){
  int i = blockIdx.x*blockDim.x + threadIdx.x;
  if (i < B*H){ hA[i] = 0.f; c[i] = 0.f; }
  if (i < B) y[i] = fio[i];
}

// ---------------- e_x = relu(temporal_x @ temp_W + temp_b) ----------------
__global__ __launch_bounds__(128) void embed_x_kernel(const float* __restrict__ tx,
    const float* __restrict__ W, const float* __restrict__ bvec, float* __restrict__ ex){
  __shared__ float xs[64];
  int bt = blockIdx.x, j = threadIdx.x;
  if (j < 64) xs[j] = tx[(size_t)bt*64 + j];
  __syncthreads();
  float a = bvec[j];
  #pragma unroll 8
  for (int k = 0; k < 64; ++k) a += xs[k]*W[k*128 + j];
  ex[(size_t)bt*128 + j] = fmaxf(a, 0.f);
}

// ---------------- e_d = relu(static_x @ stat_W + stat_b) ----------------
__global__ __launch_bounds__(128) void embed_d_kernel(const float* __restrict__ sx,
    const float* __restrict__ W, const float* __restrict__ bvec, float* __restrict__ ed){
  __shared__ float xs[32];
  int b = blockIdx.x, j = threadIdx.x;
  if (j < 32) xs[j] = sx[(size_t)b*32 + j];
  __syncthreads();
  float a = bvec[j];
  #pragma unroll 8
  for (int k = 0; k < 32; ++k) a += xs[k]*W[k*128 + j];
  ed[(size_t)b*128 + j] = fmaxf(a, 0.f);
}

// ---------------- gd = ed @ W[wrow0:wrow0+128] + bias  (B x 2048) ----------------
__global__ __launch_bounds__(256) void gd_kernel(const float* __restrict__ ed,
    const float* __restrict__ W, int wrow0, const float* __restrict__ bias,
    float* __restrict__ gd){
  __shared__ float eds[128];
  int b = blockIdx.x, tid = threadIdx.x;
  if (tid < 128) eds[tid] = ed[(size_t)b*128 + tid];
  __syncthreads();
  int n = blockIdx.y*256 + tid;
  float a = bias[n];
  #pragma unroll 8
  for (int k = 0; k < 128; ++k) a += eds[k]*W[(size_t)(wrow0 + k)*G + n];
  gd[(size_t)b*G + n] = a;
}

// ======== encoder step v2: g = gd + ex_t@Wih[0:128] + h@Whh, fused gates ========
// 256 blocks, XCD-aware decode: id&7 = XCD -> j-slab, so each XCD's L2 keeps
// a fixed 1/8 slice of the weights resident across all 128 steps.
__global__ __launch_bounds__(256) void enc_step2(
    const float* __restrict__ ex, const float* __restrict__ hist,
    const float* __restrict__ Wih, const float* __restrict__ Whh,
    const float* __restrict__ gd,
    const float* __restrict__ hin, float* __restrict__ c,
    float* __restrict__ hout, __hip_bfloat16* __restrict__ eo16, int t)
{
  __shared__ float As[2][32][44];        // [buf][b][k]
  __shared__ float Bs[2][4][16][44];     // [buf][gate][j][k]
  const int tid = threadIdx.x;
  const int tx = tid & 15;               // j within tile
  const int ty = tid >> 4;               // b-pair 0..15
  // XCD-aware decode: xcd = id&7 owns gate-column slab [xcd*64, xcd*64+64)
  const int id  = blockIdx.x;
  const int xcd = id & 7;
  const int sub = id >> 3;               // 0..31
  const int j0  = (xcd*4 + (sub & 3)) * 16;
  const int b0  = (sub >> 2) * 32;
  const int lr = tid >> 3, lk = (tid & 7) * 4;   // A-stage: row, k
  const int li1 = tid + 256;
  const int kr0 = tid >> 4,  s0 = tid & 15,  g0 = s0 >> 2, f0 = (s0 & 3)*4;
  const int kr1 = li1 >> 4,  s1 = li1 & 15,  g1 = s1 >> 2, f1 = (s1 & 3)*4;

  float acc[4][2] = {};
  const int NC = 20;                     // 4 ex-chunks + 16 h-chunks

  float4 av  = *(const float4*)&ex[((size_t)(b0+lr)*S + t)*128 + lk];
  float4 wv0 = *(const float4*)&Wih[(size_t)kr0*G + g0*512 + j0 + f0];
  float4 wv1 = *(const float4*)&Wih[(size_t)kr1*G + g1*512 + j0 + f1];
  *(float4*)&As[0][lr][lk] = av;
  Bs[0][g0][f0+0][kr0]=wv0.x; Bs[0][g0][f0+1][kr0]=wv0.y; Bs[0][g0][f0+2][kr0]=wv0.z; Bs[0][g0][f0+3][kr0]=wv0.w;
  Bs[0][g1][f1+0][kr1]=wv1.x; Bs[0][g1][f1+1][kr1]=wv1.y; Bs[0][g1][f1+2][kr1]=wv1.z; Bs[0][g1][f1+3][kr1]=wv1.w;
  __syncthreads();

  for (int ch = 0; ch < NC; ++ch){
    const int cur = ch & 1, nxt = cur ^ 1;
    const bool more = (ch+1 < NC);
    if (more){
      const int cn = ch + 1;
      if (cn < 4){
        av  = *(const float4*)&ex[((size_t)(b0+lr)*S + t)*128 + cn*32 + lk];
        wv0 = *(const float4*)&Wih[(size_t)(cn*32+kr0)*G + g0*512 + j0 + f0];
        wv1 = *(const float4*)&Wih[(size_t)(cn*32+kr1)*G + g1*512 + j0 + f1];
      } else {
        av  = *(const float4*)&hin[(size_t)(b0+lr)*H + (cn-4)*32 + lk];
        wv0 = *(const float4*)&Whh[(size_t)((cn-4)*32+kr0)*G + g0*512 + j0 + f0];
        wv1 = *(const float4*)&Whh[(size_t)((cn-4)*32+kr1)*G + g1*512 + j0 + f1];
      }
    }
    #pragma unroll
    for (int u = 0; u < 8; ++u){
      const int k0 = u*4;
      float4 a0 = *(const float4*)&As[cur][ty*2+0][k0];
      float4 a1 = *(const float4*)&As[cur][ty*2+1][k0];
      #pragma unroll
      for (int g = 0; g < 4; ++g){
        float4 w = *(const float4*)&Bs[cur][g][tx][k0];
        acc[g][0] += a0.x*w.x + a0.y*w.y + a0.z*w.z + a0.w*w.w;
        acc[g][1] += a1.x*w.x + a1.y*w.y + a1.z*w.z + a1.w*w.w;
      }
    }
    if (more){
      *(float4*)&As[nxt][lr][lk] = av;
      Bs[nxt][g0][f0+0][kr0]=wv0.x; Bs[nxt][g0][f0+1][kr0]=wv0.y; Bs[nxt][g0][f0+2][kr0]=wv0.z; Bs[nxt][g0][f0+3][kr0]=wv0.w;
      Bs[nxt][g1][f1+0][kr1]=wv1.x; Bs[nxt][g1][f1+1][kr1]=wv1.y; Bs[nxt][g1][f1+2][kr1]=wv1.z; Bs[nxt][g1][f1+3][kr1]=wv1.w;
    }
    __syncthreads();
  }

  const int j_ = j0 + tx;
  #pragma unroll
  for (int bp = 0; bp < 2; ++bp){
    const int b_ = b0 + ty*2 + bp;
    const float hv = hist[(size_t)b_*S + t];
    float gate[4];
    #pragma unroll
    for (int g = 0; g < 4; ++g){
      const int n = g*512 + j_;
      gate[g] = acc[g][bp] + gd[(size_t)b_*G + n] + hv*Wih[(size_t)256*G + n];
    }
    const size_t ci = (size_t)b_*H + j_;
    float cn = sigmoidf_(gate[1])*c[ci] + sigmoidf_(gate[0])*tanhf(gate[2]);
    float hn = sigmoidf_(gate[3])*tanhf(cn);
    c[ci] = cn;
    hout[ci] = hn;
    eo16[((size_t)b_*S + t)*H + j_] = __float2bfloat16(hn);
  }
}

// ======== decoder step v2: g = gdd + y*Wy + a*Wa + h@Whh ========
__global__ __launch_bounds__(256) void dec_step2(
    const float* __restrict__ y, const float* __restrict__ fut,
    const float* __restrict__ Wih, const float* __restrict__ Whh,
    const float* __restrict__ gdd,
    const float* __restrict__ hin, float* __restrict__ c,
    float* __restrict__ hout, int t)
{
  __shared__ float As[2][32][44];
  __shared__ float Bs[2][4][16][44];
  const int tid = threadIdx.x;
  const int tx = tid & 15;
  const int ty = tid >> 4;
  const int id  = blockIdx.x;
  const int xcd = id & 7;
  const int sub = id >> 3;
  const int j0  = (xcd*4 + (sub & 3)) * 16;
  const int b0  = (sub >> 2) * 32;
  const int lr = tid >> 3, lk = (tid & 7) * 4;
  const int li1 = tid + 256;
  const int kr0 = tid >> 4,  s0 = tid & 15,  g0 = s0 >> 2, f0 = (s0 & 3)*4;
  const int kr1 = li1 >> 4,  s1 = li1 & 15,  g1 = s1 >> 2, f1 = (s1 & 3)*4;

  float acc[4][2] = {};
  const int NC = 16;                     // 16 h-chunks (K=512)

  float4 av  = *(const float4*)&hin[(size_t)(b0+lr)*H + lk];
  float4 wv0 = *(const float4*)&Whh[(size_t)kr0*G + g0*512 + j0 + f0];
  float4 wv1 = *(const float4*)&Whh[(size_t)kr1*G + g1*512 + j0 + f1];
  *(float4*)&As[0][lr][lk] = av;
  Bs[0][g0][f0+0][kr0]=wv0.x; Bs[0][g0][f0+1][kr0]=wv0.y; Bs[0][g0][f0+2][kr0]=wv0.z; Bs[0][g0][f0+3][kr0]=wv0.w;
  Bs[0][g1][f1+0][kr1]=wv1.x; Bs[0][g1][f1+1][kr1]=wv1.y; Bs[0][g1][f1+2][kr1]=wv1.z; Bs[0][g1][f1+3][kr1]=wv1.w;
  __syncthreads();

  for (int ch = 0; ch < NC; ++ch){
    const int cur = ch & 1, nxt = cur ^ 1;
    const bool more = (ch+1 < NC);
    if (more){
      const int cn = ch + 1;
      av  = *(const float4*)&hin[(size_t)(b0+lr)*H + cn*32 + lk];
      wv0 = *(const float4*)&Whh[(size_t)(cn*32+kr0)*G + g0*512 + j0 + f0];
      wv1 = *(const float4*)&Whh[(size_t)(cn*32+kr1)*G + g1*512 + j0 + f1];
    }
    #pragma unroll
    for (int u = 0; u < 8; ++u){
      const int k0 = u*4;
      float4 a0 = *(const float4*)&As[cur][ty*2+0][k0];
      float4 a1 = *(const float4*)&As[cur][ty*2+1][k0];
      #pragma unroll
      for (int g = 0; g < 4; ++g){
        float4 w = *(const float4*)&Bs[cur][g][tx][k0];
        acc[g][0] += a0.x*w.x + a0.y*w.y + a0.z*w.z + a0.w*w.w;
        acc[g][1] += a1.x*w.x + a1.y*w.y + a1.z*w.z + a1.w*w.w;
      }
    }
    if (more){
      *(float4*)&As[nxt][lr][lk] = av;
      Bs[nxt][g0][f0+0][kr0]=wv0.x; Bs[nxt][g0][f0+1][kr0]=wv0.y; Bs[nxt][g0][f0+2][kr0]=wv0.z; Bs[nxt][g0][f0+3][kr0]=wv0.w;
      Bs[nxt][g1][f1+0][kr1]=wv1.x; Bs[nxt][g1][f1+1][kr1]=wv1.y; Bs[nxt][g1][f1+2][kr1]=wv1.z; Bs[nxt][g1][f1+3][kr1]=wv1.w;
    }
    __syncthreads();
  }

  const int j_ = j0 + tx;
  #pragma unroll
  for (int bp = 0; bp < 2; ++bp){
    const int b_ = b0 + ty*2 + bp;
    const float yv  = y[b_];
    const float av_ = fut[(size_t)b_*16 + t];
    float gate[4];
    #pragma unroll
    for (int g = 0; g < 4; ++g){
      const int n = g*512 + j_;
      gate[g] = acc[g][bp] + gdd[(size_t)b_*G + n]
              + yv*Wih[(size_t)128*G + n] + av_*Wih[(size_t)129*G + n];
    }
    const size_t ci = (size_t)b_*H + j_;
    float cn = sigmoidf_(gate[1])*c[ci] + sigmoidf_(gate[0])*tanhf(gate[2]);
    float hn = sigmoidf_(gate[3])*tanhf(cn);
    c[ci] = cn;
    hout[ci] = hn;
  }
}

// ---------------- propensity logits + enc_We (one pass over eo16) ----------------
__global__ __launch_bounds__(256) void prop_we_kernel(
    const __hip_bfloat16* __restrict__ eo, const float* __restrict__ propW,
    const float* __restrict__ propb, const float* __restrict__ attnW,
    float* __restrict__ prop_out, float* __restrict__ encWe)
{
  int row = blockIdx.x*4 + (threadIdx.x >> 6);
  int lane = threadIdx.x & 63;
  const __hip_bfloat16* e = &eo[(size_t)row*H];
  float ap = 0.f, aw = 0.f;
  #pragma unroll
  for (int i = 0; i < 8; ++i){
    float v = __bfloat162float(e[lane + i*64]);
    ap += v*propW[lane + i*64];
    aw += v*attnW[512 + lane + i*64];
  }
  #pragma unroll
  for (int off = 32; off; off >>= 1){ ap += __shfl_down(ap, off); aw += __shfl_down(aw, off); }
  if (lane == 0){
    prop_out[row] = ap + propb[0];
    encWe[row] = aw;
  }
}

// ---------------- attention + context + prediction (per decoder step) ----------------
__global__ __launch_bounds__(256) void attn_pred_kernel(
    const __hip_bfloat16* __restrict__ eo, const float* __restrict__ encWe,
    const float* __restrict__ h,
    const float* __restrict__ attnW, const float* __restrict__ attnb,
    const float* __restrict__ outW, const float* __restrict__ outb,
    const float* __restrict__ fut,
    float* __restrict__ y, float* __restrict__ out, int t)
{
  int b = blockIdx.x, tid = threadIdx.x;
  __shared__ float hWi[512];
  __shared__ float red[256];
  __shared__ float sc[128];
  __shared__ float smax, ssum, shWh;

  float hv0 = h[(size_t)b*H + tid];
  float hv1 = h[(size_t)b*H + 256 + tid];
  hWi[tid]       = hv0 * attnW[1024 + tid];
  hWi[tid + 256] = hv1 * attnW[1024 + 256 + tid];
  red[tid] = hv0*attnW[tid] + hv1*attnW[256 + tid];
  __syncthreads();
  for (int off = 128; off; off >>= 1){
    if (tid < off) red[tid] += red[tid + off];
    __syncthreads();
  }
  if (tid == 0) shWh = red[0];
  __syncthreads();

  int lane = tid & 63;
  for (int s = (tid >> 6); s < S; s += 4){
    const __hip_bfloat16* e = &eo[((size_t)b*S + s)*H];
    float a = 0.f;
    #pragma unroll
    for (int i = 0; i < 8; ++i) a += __bfloat162float(e[lane + i*64])*hWi[lane + i*64];
    #pragma unroll
    for (int off = 32; off; off >>= 1) a += __shfl_down(a, off);
    if (lane == 0) sc[s] = tanhf(shWh + encWe[(size_t)b*S + s] + a + attnb[0]);
  }
  __syncthreads();

  if (tid < 64){
    float m = fmaxf(sc[tid], sc[tid + 64]);
    #pragma unroll
    for (int off = 32; off; off >>= 1) m = fmaxf(m, __shfl_down(m, off));
    if (tid == 0) smax = m;
  }
  __syncthreads();
  if (tid < 128){ float e = expf(sc[tid] - smax); sc[tid] = e; red[tid] = e; }
  else red[tid] = 0.f;
  __syncthreads();
  for (int off = 128; off; off >>= 1){
    if (tid < off) red[tid] += red[tid + off];
    __syncthreads();
  }
  if (tid == 0) ssum = red[0];
  __syncthreads();
  float inv = 1.f / ssum;

  float c0 = 0.f, c1 = 0.f;
  for (int s = 0; s < S; ++s){
    float w = sc[s];
    const __hip_bfloat16* e = &eo[((size_t)b*S + s)*H];
    c0 += w*__bfloat162float(e[tid]);
    c1 += w*__bfloat162float(e[tid + 256]);
  }
  c0 *= inv; c1 *= inv;

  red[tid] = hv0*outW[tid] + hv1*outW[256 + tid] + c0*outW[512 + tid] + c1*outW[768 + tid];
  __syncthreads();
  for (int off = 128; off; off >>= 1){
    if (tid < off) red[tid] += red[tid + off];
    __syncthreads();
  }
  if (tid == 0){
    float at = fut[(size_t)b*16 + t];
    float p = red[0] + at*outW[1024] + outb[0];
    y[b] = p;
    out[(size_t)b*16 + t] = p;
  }
}

extern "C" void kernel_launch(void* const* d_in, const int* in_sizes, int n_in,
                              void* d_out, int out_size, void* d_ws, size_t ws_size,
                              hipStream_t stream)
{
  const float* temporal_x = (const float*)d_in[0];
  const float* static_x   = (const float*)d_in[1];
  const float* hist       = (const float*)d_in[2];
  const float* fut        = (const float*)d_in[3];
  const float* fio        = (const float*)d_in[4];
  const float* temp_W = (const float*)d_in[5];
  const float* temp_b = (const float*)d_in[6];
  const float* stat_W = (const float*)d_in[7];
  const float* stat_b = (const float*)d_in[8];
  const float* eWih = (const float*)d_in[9];
  const float* eWhh = (const float*)d_in[10];
  const float* eb   = (const float*)d_in[11];
  const float* attnW = (const float*)d_in[12];
  const float* attnb = (const float*)d_in[13];
  const float* dWih = (const float*)d_in[14];
  const float* dWhh = (const float*)d_in[15];
  const float* dbias = (const float*)d_in[16];
  const float* outW = (const float*)d_in[17];
  const float* outb = (const float*)d_in[18];
  const float* propW = (const float*)d_in[19];
  const float* propb = (const float*)d_in[20];
  float* out = (float*)d_out;   // fp32: [B*16 preds][B*S propensity]

  // workspace layout (floats), ~54.3 MB total
  float* ws = (float*)d_ws;
  float* ex    = ws;                          // B*S*128 = 4,194,304
  float* ed    = ex + (size_t)B*S*128;        // B*128
  float* hA    = ed + (size_t)B*128;          // B*H
  float* hB    = hA + (size_t)B*H;            // B*H
  float* cb    = hB + (size_t)B*H;            // B*H
  float* encWe = cb + (size_t)B*H;            // B*S
  float* yb    = encWe + (size_t)B*S;         // B
  float* gd_e  = yb + B;                      // B*G = 524,288
  __hip_bfloat16* eo16 = (__hip_bfloat16*)(gd_e + (size_t)B*G); // B*S*H bf16
  // decoder-phase reuse of the (dead) ex region:
  float* gd_d  = ex;                          // B*G
  float* dh0   = ex + (size_t)B*G;            // B*H
  float* dh1   = dh0 + (size_t)B*H;           // B*H

  init_kernel<<<(B*H + 255)/256, 256, 0, stream>>>(hA, cb, yb, fio);
  embed_x_kernel<<<B*S, 128, 0, stream>>>(temporal_x, temp_W, temp_b, ex);
  embed_d_kernel<<<B, 128, 0, stream>>>(static_x, stat_W, stat_b, ed);
  gd_kernel<<<dim3(B,8), 256, 0, stream>>>(ed, eWih, 128, eb, gd_e);

  // encoder: even t reads hA writes hB; odd t reads hB writes hA. h_n ends in hA.
  for (int t = 0; t < S; ++t){
    const float* hin = (t & 1) ? hB : hA;
    float* hout      = (t & 1) ? hA : hB;
    enc_step2<<<256, 256, 0, stream>>>(ex, hist, eWih, eWhh, gd_e,
                                       hin, cb, hout, eo16, t);
  }

  // gd_d overwrites ex region — only after the encoder is done with ex.
  gd_kernel<<<dim3(B,8), 256, 0, stream>>>(ed, dWih, 0, dbias, gd_d);
  prop_we_kernel<<<(B*S)/4, 256, 0, stream>>>(eo16, propW, propb, attnW, out + B*16, encWe);

  for (int t = 0; t < 16; ++t){
    const float* hp = (t == 0) ? hA : ((t & 1) ? dh0 : dh1);
    float* ho = (t & 1) ? dh1 : dh0;
    dec_step2<<<256, 256, 0, stream>>>(yb, fut, dWih, dWhh, gd_d,
                                       hp, cb, ho, t);
    attn_pred_kernel<<<B, 256, 0, stream>>>(eo16, encWe, ho, attnW, attnb, outW, outb,
                                            fut, yb, out, t);
  }
}

// Round 6
// 2158.610 us; speedup vs baseline: 4.1790x; 2.0654x over previous
//
#include <hip/hip_runtime.h>
#include <hip/hip_bf16.h>
#include <cstddef>

#define B 256
#define S 128
#define H 512
#define G 2048

typedef __attribute__((ext_vector_type(8))) short short8;
typedef __attribute__((ext_vector_type(4))) float f32x4;

__device__ __forceinline__ float sigmoidf_(float x){ return 1.f/(1.f+expf(-x)); }

// ---------------- init: zero c and h16A, y = future_init_outcome ----------------
__global__ void init_kernel(float* __restrict__ c, unsigned* __restrict__ h16A_u,
                            float* __restrict__ y, const float* __restrict__ fio){
  int i = blockIdx.x*blockDim.x + threadIdx.x;
  if (i < B*H) c[i] = 0.f;
  if (i < B*H/2) h16A_u[i] = 0u;      // two bf16 zeros
  if (i < B) y[i] = fio[i];
}

// ---------------- e_x = relu(temporal_x @ temp_W + temp_b) -> bf16 ----------------
__global__ __launch_bounds__(128) void embed_x_kernel(const float* __restrict__ tx,
    const float* __restrict__ W, const float* __restrict__ bvec,
    __hip_bfloat16* __restrict__ ex16){
  __shared__ float xs[64];
  int bt = blockIdx.x, j = threadIdx.x;
  if (j < 64) xs[j] = tx[(size_t)bt*64 + j];
  __syncthreads();
  float a = bvec[j];
  #pragma unroll 8
  for (int k = 0; k < 64; ++k) a += xs[k]*W[k*128 + j];
  ex16[(size_t)bt*128 + j] = __float2bfloat16(fmaxf(a, 0.f));
}

// ---------------- e_d = relu(static_x @ stat_W + stat_b) (fp32) ----------------
__global__ __launch_bounds__(128) void embed_d_kernel(const float* __restrict__ sx,
    const float* __restrict__ W, const float* __restrict__ bvec, float* __restrict__ ed){
  __shared__ float xs[32];
  int b = blockIdx.x, j = threadIdx.x;
  if (j < 32) xs[j] = sx[(size_t)b*32 + j];
  __syncthreads();
  float a = bvec[j];
  #pragma unroll 8
  for (int k = 0; k < 32; ++k) a += xs[k]*W[k*128 + j];
  ed[(size_t)b*128 + j] = fmaxf(a, 0.f);
}

// ---------------- gd = ed @ W[wrow0:wrow0+128] + bias  (B x 2048, fp32) ----------------
__global__ __launch_bounds__(256) void gd_kernel(const float* __restrict__ ed,
    const float* __restrict__ W, int wrow0, const float* __restrict__ bias,
    float* __restrict__ gd){
  __shared__ float eds[128];
  int b = blockIdx.x, tid = threadIdx.x;
  if (tid < 128) eds[tid] = ed[(size_t)b*128 + tid];
  __syncthreads();
  int n = blockIdx.y*256 + tid;
  float a = bias[n];
  #pragma unroll 8
  for (int k = 0; k < 128; ++k) a += eds[k]*W[(size_t)(wrow0 + k)*G + n];
  gd[(size_t)b*G + n] = a;
}

// ---- weight transpose to bf16 n-major: dst[n][k], src(k,n)= k<rowsA ? A[k][n] : Bm[k-rowsA][n]
__global__ __launch_bounds__(256) void wtrans_kernel(
    const float* __restrict__ A, int rowsA, const float* __restrict__ Bm,
    __hip_bfloat16* __restrict__ dst, int Ktot)
{
  __shared__ float tile[64][65];
  const int k0 = blockIdx.x*64, n0 = blockIdx.y*64;
  const int tid = threadIdx.x;
  const int tn = tid & 63, tq = tid >> 6;     // tq in 0..3
  #pragma unroll
  for (int i = 0; i < 16; ++i){
    int k = k0 + tq*16 + i;
    float v = (k < rowsA) ? A[(size_t)k*G + n0 + tn] : Bm[(size_t)(k-rowsA)*G + n0 + tn];
    tile[k - k0][tn] = v;
  }
  __syncthreads();
  #pragma unroll
  for (int i = 0; i < 16; ++i){
    int n = n0 + tq*16 + i;
    dst[(size_t)n*Ktot + k0 + tn] = __float2bfloat16(tile[tn][tq*16 + i]);
  }
}

// ======== encoder step v3: bf16 MFMA.  g = [ex_t,h]@W16 + gd + hist*Wr256 ========
// 256 blocks (XCD-swizzled), 256 thr = 4 waves. Block tile: 64 b x (4 gates x 8 h-cols).
__global__ __launch_bounds__(256) void enc_step3(
    const __hip_bfloat16* __restrict__ ex16,   // [B][S][128]
    const __hip_bfloat16* __restrict__ hin,    // [B][512]
    const __hip_bfloat16* __restrict__ W16,    // [2048][640] n-major
    const float* __restrict__ gd,              // [B][2048]
    const float* __restrict__ Wr256,           // fp32 row Wih[256][*]
    const float* __restrict__ hist,            // [B][S]
    float* __restrict__ c,
    __hip_bfloat16* __restrict__ hout16,
    __hip_bfloat16* __restrict__ eo16,
    int t)
{
  __shared__ unsigned short As[2][4][64][8];   // 8 KB  [buf][kg][b][kk]
  __shared__ unsigned short Bs[2][4][32][8];   // 4 KB  [buf][kg][cc][kk]
  __shared__ float gsc[4][8][66];              // gate scratch
  const int tid = threadIdx.x;
  const int id  = blockIdx.x;
  const int xcd = id & 7, sub = id >> 3;
  const int jgrp = xcd*8 + (sub & 7);          // 0..63 -> h-col slab
  const int bgrp = sub >> 3;                   // 0..3
  const int b0 = bgrp*64, j0 = jgrp*8;
  const int l  = tid & 63;
  const int wid = tid >> 6, wm = wid & 1, wn = wid >> 1;
  // staging decode
  const int sb = tid & 63, skg = tid >> 6;                 // A: 64 b x 4 kg
  const int cc = tid & 31, bkg = (tid >> 5) & 3;           // B: 32 cc x 4 kg (tid<128)
  const int bn = (cc >> 3)*512 + j0 + (cc & 7);            // global gate col

  f32x4 acc0 = {0.f,0.f,0.f,0.f}, acc1 = {0.f,0.f,0.f,0.f};

  const size_t exrow = ((size_t)(b0+sb)*S + t)*128;
  const size_t hrow  = (size_t)(b0+sb)*H;
  const size_t wrow  = (size_t)bn*640;

  uint4 aReg, bReg;
  aReg = *(const uint4*)&ex16[exrow + skg*8];
  if (tid < 128) bReg = *(const uint4*)&W16[wrow + bkg*8];
  *(uint4*)&As[0][skg][sb][0] = aReg;
  if (tid < 128) *(uint4*)&Bs[0][bkg][cc][0] = bReg;
  __syncthreads();

  const int NC = 20;
  for (int ch = 0; ch < NC; ++ch){
    const int cur = ch & 1, nxt = cur ^ 1;
    const bool more = (ch+1 < NC);
    if (more){
      const int k = (ch+1)*32 + skg*8;
      aReg = (k < 128) ? *(const uint4*)&ex16[exrow + k]
                       : *(const uint4*)&hin[hrow + (k-128)];
      if (tid < 128) bReg = *(const uint4*)&W16[wrow + (ch+1)*32 + bkg*8];
    }
    short8 af0 = *(const short8*)&As[cur][l>>4][wm*32 + (l&15)][0];
    short8 af1 = *(const short8*)&As[cur][l>>4][wm*32 + 16 + (l&15)][0];
    short8 bfr = *(const short8*)&Bs[cur][l>>4][wn*16 + (l&15)][0];
    acc0 = __builtin_amdgcn_mfma_f32_16x16x32_bf16(af0, bfr, acc0, 0,0,0);
    acc1 = __builtin_amdgcn_mfma_f32_16x16x32_bf16(af1, bfr, acc1, 0,0,0);
    if (more){
      *(uint4*)&As[nxt][skg][sb][0] = aReg;
      if (tid < 128) *(uint4*)&Bs[nxt][bkg][cc][0] = bReg;
    }
    __syncthreads();
  }

  // gates to LDS scratch: D col = lane&15 -> (gate pair, jj); D row = (lane>>4)*4+reg
  {
    const int jj = l & 7;
    const int g  = wn*2 + ((l>>3)&1);
    #pragma unroll
    for (int r = 0; r < 4; ++r){
      gsc[g][jj][wm*32 +      (l>>4)*4 + r] = acc0[r];
      gsc[g][jj][wm*32 + 16 + (l>>4)*4 + r] = acc1[r];
    }
  }
  __syncthreads();

  #pragma unroll
  for (int p = 0; p < 2; ++p){
    const int pp = tid + p*256;
    const int jj = pp & 7, bl = pp >> 3;
    const int b_ = b0 + bl, j_ = j0 + jj;
    const float hv = hist[(size_t)b_*S + t];
    const float* gdr = &gd[(size_t)b_*G];
    float gi = gsc[0][jj][bl] + gdr[       j_] + hv*Wr256[       j_];
    float gf = gsc[1][jj][bl] + gdr[ 512 + j_] + hv*Wr256[ 512 + j_];
    float gg = gsc[2][jj][bl] + gdr[1024 + j_] + hv*Wr256[1024 + j_];
    float go = gsc[3][jj][bl] + gdr[1536 + j_] + hv*Wr256[1536 + j_];
    const size_t ci = (size_t)b_*H + j_;
    float cn = sigmoidf_(gf)*c[ci] + sigmoidf_(gi)*tanhf(gg);
    float hn = sigmoidf_(go)*tanhf(cn);
    c[ci] = cn;
    hout16[ci] = __float2bfloat16(hn);
    eo16[((size_t)b_*S + t)*H + j_] = __float2bfloat16(hn);
  }
}

// ======== decoder step v3: bf16 MFMA. g = h@W16D + gdd + y*Wy + a*Wa ========
__global__ __launch_bounds__(256) void dec_step3(
    const __hip_bfloat16* __restrict__ hin,    // [B][512]
    const __hip_bfloat16* __restrict__ W16,    // [2048][512] n-major (dWhh^T)
    const float* __restrict__ gdd,             // [B][2048]
    const float* __restrict__ Wy,              // dWih row 128
    const float* __restrict__ Wa,              // dWih row 129
    const float* __restrict__ y, const float* __restrict__ fut,
    float* __restrict__ c,
    float* __restrict__ hout32,
    __hip_bfloat16* __restrict__ hout16,
    int t)
{
  __shared__ unsigned short As[2][4][64][8];
  __shared__ unsigned short Bs[2][4][32][8];
  __shared__ float gsc[4][8][66];
  const int tid = threadIdx.x;
  const int id  = blockIdx.x;
  const int xcd = id & 7, sub = id >> 3;
  const int jgrp = xcd*8 + (sub & 7);
  const int bgrp = sub >> 3;
  const int b0 = bgrp*64, j0 = jgrp*8;
  const int l  = tid & 63;
  const int wid = tid >> 6, wm = wid & 1, wn = wid >> 1;
  const int sb = tid & 63, skg = tid >> 6;
  const int cc = tid & 31, bkg = (tid >> 5) & 3;
  const int bn = (cc >> 3)*512 + j0 + (cc & 7);

  f32x4 acc0 = {0.f,0.f,0.f,0.f}, acc1 = {0.f,0.f,0.f,0.f};
  const size_t hrow = (size_t)(b0+sb)*H;
  const size_t wrow = (size_t)bn*512;

  uint4 aReg, bReg;
  aReg = *(const uint4*)&hin[hrow + skg*8];
  if (tid < 128) bReg = *(const uint4*)&W16[wrow + bkg*8];
  *(uint4*)&As[0][skg][sb][0] = aReg;
  if (tid < 128) *(uint4*)&Bs[0][bkg][cc][0] = bReg;
  __syncthreads();

  const int NC = 16;
  for (int ch = 0; ch < NC; ++ch){
    const int cur = ch & 1, nxt = cur ^ 1;
    const bool more = (ch+1 < NC);
    if (more){
      const int k = (ch+1)*32 + skg*8;
      aReg = *(const uint4*)&hin[hrow + k];
      if (tid < 128) bReg = *(const uint4*)&W16[wrow + (ch+1)*32 + bkg*8];
    }
    short8 af0 = *(const short8*)&As[cur][l>>4][wm*32 + (l&15)][0];
    short8 af1 = *(const short8*)&As[cur][l>>4][wm*32 + 16 + (l&15)][0];
    short8 bfr = *(const short8*)&Bs[cur][l>>4][wn*16 + (l&15)][0];
    acc0 = __builtin_amdgcn_mfma_f32_16x16x32_bf16(af0, bfr, acc0, 0,0,0);
    acc1 = __builtin_amdgcn_mfma_f32_16x16x32_bf16(af1, bfr, acc1, 0,0,0);
    if (more){
      *(uint4*)&As[nxt][skg][sb][0] = aReg;
      if (tid < 128) *(uint4*)&Bs[nxt][bkg][cc][0] = bReg;
    }
    __syncthreads();
  }

  {
    const int jj = l & 7;
    const int g  = wn*2 + ((l>>3)&1);
    #pragma unroll
    for (int r = 0; r < 4; ++r){
      gsc[g][jj][wm*32 +      (l>>4)*4 + r] = acc0[r];
      gsc[g][jj][wm*32 + 16 + (l>>4)*4 + r] = acc1[r];
    }
  }
  __syncthreads();

  #pragma unroll
  for (int p = 0; p < 2; ++p){
    const int pp = tid + p*256;
    const int jj = pp & 7, bl = pp >> 3;
    const int b_ = b0 + bl, j_ = j0 + jj;
    const float yv = y[b_];
    const float av = fut[(size_t)b_*16 + t];
    const float* gdr = &gdd[(size_t)b_*G];
    float gi = gsc[0][jj][bl] + gdr[       j_] + yv*Wy[       j_] + av*Wa[       j_];
    float gf = gsc[1][jj][bl] + gdr[ 512 + j_] + yv*Wy[ 512 + j_] + av*Wa[ 512 + j_];
    float gg = gsc[2][jj][bl] + gdr[1024 + j_] + yv*Wy[1024 + j_] + av*Wa[1024 + j_];
    float go = gsc[3][jj][bl] + gdr[1536 + j_] + yv*Wy[1536 + j_] + av*Wa[1536 + j_];
    const size_t ci = (size_t)b_*H + j_;
    float cn = sigmoidf_(gf)*c[ci] + sigmoidf_(gi)*tanhf(gg);
    float hn = sigmoidf_(go)*tanhf(cn);
    c[ci] = cn;
    hout32[ci] = hn;
    hout16[ci] = __float2bfloat16(hn);
  }
}

// ---------------- propensity logits + enc_We (one pass over eo16) ----------------
__global__ __launch_bounds__(256) void prop_we_kernel(
    const __hip_bfloat16* __restrict__ eo, const float* __restrict__ propW,
    const float* __restrict__ propb, const float* __restrict__ attnW,
    float* __restrict__ prop_out, float* __restrict__ encWe)
{
  int row = blockIdx.x*4 + (threadIdx.x >> 6);
  int lane = threadIdx.x & 63;
  const __hip_bfloat16* e = &eo[(size_t)row*H];
  float ap = 0.f, aw = 0.f;
  #pragma unroll
  for (int i = 0; i < 8; ++i){
    float v = __bfloat162float(e[lane + i*64]);
    ap += v*propW[lane + i*64];
    aw += v*attnW[512 + lane + i*64];
  }
  #pragma unroll
  for (int off = 32; off; off >>= 1){ ap += __shfl_down(ap, off); aw += __shfl_down(aw, off); }
  if (lane == 0){
    prop_out[row] = ap + propb[0];
    encWe[row] = aw;
  }
}

// ---------------- attention + context + prediction (per decoder step) ----------------
__global__ __launch_bounds__(256) void attn_pred_kernel(
    const __hip_bfloat16* __restrict__ eo, const float* __restrict__ encWe,
    const float* __restrict__ h,
    const float* __restrict__ attnW, const float* __restrict__ attnb,
    const float* __restrict__ outW, const float* __restrict__ outb,
    const float* __restrict__ fut,
    float* __restrict__ y, float* __restrict__ out, int t)
{
  int b = blockIdx.x, tid = threadIdx.x;
  __shared__ float hWi[512];
  __shared__ float red[256];
  __shared__ float sc[128];
  __shared__ float smax, ssum, shWh;

  float hv0 = h[(size_t)b*H + tid];
  float hv1 = h[(size_t)b*H + 256 + tid];
  hWi[tid]       = hv0 * attnW[1024 + tid];
  hWi[tid + 256] = hv1 * attnW[1024 + 256 + tid];
  red[tid] = hv0*attnW[tid] + hv1*attnW[256 + tid];
  __syncthreads();
  for (int off = 128; off; off >>= 1){
    if (tid < off) red[tid] += red[tid + off];
    __syncthreads();
  }
  if (tid == 0) shWh = red[0];
  __syncthreads();

  int lane = tid & 63;
  for (int s = (tid >> 6); s < S; s += 4){
    const __hip_bfloat16* e = &eo[((size_t)b*S + s)*H];
    float a = 0.f;
    #pragma unroll
    for (int i = 0; i < 8; ++i) a += __bfloat162float(e[lane + i*64])*hWi[lane + i*64];
    #pragma unroll
    for (int off = 32; off; off >>= 1) a += __shfl_down(a, off);
    if (lane == 0) sc[s] = tanhf(shWh + encWe[(size_t)b*S + s] + a + attnb[0]);
  }
  __syncthreads();

  if (tid < 64){
    float m = fmaxf(sc[tid], sc[tid + 64]);
    #pragma unroll
    for (int off = 32; off; off >>= 1) m = fmaxf(m, __shfl_down(m, off));
    if (tid == 0) smax = m;
  }
  __syncthreads();
  if (tid < 128){ float e = expf(sc[tid] - smax); sc[tid] = e; red[tid] = e; }
  else red[tid] = 0.f;
  __syncthreads();
  for (int off = 128; off; off >>= 1){
    if (tid < off) red[tid] += red[tid + off];
    __syncthreads();
  }
  if (tid == 0) ssum = red[0];
  __syncthreads();
  float inv = 1.f / ssum;

  float c0 = 0.f, c1 = 0.f;
  for (int s = 0; s < S; ++s){
    float w = sc[s];
    const __hip_bfloat16* e = &eo[((size_t)b*S + s)*H];
    c0 += w*__bfloat162float(e[tid]);
    c1 += w*__bfloat162float(e[tid + 256]);
  }
  c0 *= inv; c1 *= inv;

  red[tid] = hv0*outW[tid] + hv1*outW[256 + tid] + c0*outW[512 + tid] + c1*outW[768 + tid];
  __syncthreads();
  for (int off = 128; off; off >>= 1){
    if (tid < off) red[tid] += red[tid + off];
    __syncthreads();
  }
  if (tid == 0){
    float at = fut[(size_t)b*16 + t];
    float p = red[0] + at*outW[1024] + outb[0];
    y[b] = p;
    out[(size_t)b*16 + t] = p;
  }
}

extern "C" void kernel_launch(void* const* d_in, const int* in_sizes, int n_in,
                              void* d_out, int out_size, void* d_ws, size_t ws_size,
                              hipStream_t stream)
{
  const float* temporal_x = (const float*)d_in[0];
  const float* static_x   = (const float*)d_in[1];
  const float* hist       = (const float*)d_in[2];
  const float* fut        = (const float*)d_in[3];
  const float* fio        = (const float*)d_in[4];
  const float* temp_W = (const float*)d_in[5];
  const float* temp_b = (const float*)d_in[6];
  const float* stat_W = (const float*)d_in[7];
  const float* stat_b = (const float*)d_in[8];
  const float* eWih = (const float*)d_in[9];
  const float* eWhh = (const float*)d_in[10];
  const float* eb   = (const float*)d_in[11];
  const float* attnW = (const float*)d_in[12];
  const float* attnb = (const float*)d_in[13];
  const float* dWih = (const float*)d_in[14];
  const float* dWhh = (const float*)d_in[15];
  const float* dbias = (const float*)d_in[16];
  const float* outW = (const float*)d_in[17];
  const float* outb = (const float*)d_in[18];
  const float* propW = (const float*)d_in[19];
  const float* propb = (const float*)d_in[20];
  float* out = (float*)d_out;   // fp32: [B*16 preds][B*S propensity]

  // ---- workspace layout: fp32 section then bf16 section (~52.7 MB) ----
  float* ws = (float*)d_ws;
  float* ed    = ws;                           // B*128   = 32768
  float* gd_e  = ed    + (size_t)B*128;        // B*G
  float* gd_d  = gd_e  + (size_t)B*G;          // B*G
  float* cb    = gd_d  + (size_t)B*G;          // B*H
  float* encWe = cb    + (size_t)B*H;          // B*S
  float* yb    = encWe + (size_t)B*S;          // B
  float* dh32  = yb    + B;                    // B*H
  __hip_bfloat16* bf = (__hip_bfloat16*)(dh32 + (size_t)B*H);
  __hip_bfloat16* ex16 = bf;                              // B*S*128
  __hip_bfloat16* eo16 = ex16 + (size_t)B*S*128;          // B*S*H
  __hip_bfloat16* h16A = eo16 + (size_t)B*S*H;            // B*H
  __hip_bfloat16* h16B = h16A + (size_t)B*H;              // B*H
  __hip_bfloat16* W16E = h16B + (size_t)B*H;              // 2048*640
  __hip_bfloat16* W16D = W16E + (size_t)G*640;            // 2048*512

  init_kernel<<<(B*H + 255)/256, 256, 0, stream>>>(cb, (unsigned*)h16A, yb, fio);
  embed_x_kernel<<<B*S, 128, 0, stream>>>(temporal_x, temp_W, temp_b, ex16);
  embed_d_kernel<<<B, 128, 0, stream>>>(static_x, stat_W, stat_b, ed);
  gd_kernel<<<dim3(B,8), 256, 0, stream>>>(ed, eWih, 128, eb, gd_e);
  gd_kernel<<<dim3(B,8), 256, 0, stream>>>(ed, dWih, 0, dbias, gd_d);
  wtrans_kernel<<<dim3(10,32), 256, 0, stream>>>(eWih, 128, eWhh, W16E, 640);
  wtrans_kernel<<<dim3(8,32),  256, 0, stream>>>(dWhh, 0,   dWhh, W16D, 512);

  // encoder: t reads (t&1 ? h16B : h16A), writes the other. Final h_n in h16A.
  for (int t = 0; t < S; ++t){
    const __hip_bfloat16* hin = (t & 1) ? h16B : h16A;
    __hip_bfloat16* hout      = (t & 1) ? h16A : h16B;
    enc_step3<<<256, 256, 0, stream>>>(ex16, hin, W16E, gd_e, eWih + (size_t)256*G,
                                       hist, cb, hout, eo16, t);
  }

  prop_we_kernel<<<(B*S)/4, 256, 0, stream>>>(eo16, propW, propb, attnW, out + B*16, encWe);

  // decoder: t reads (t&1 ? h16B : h16A) — t=0 reads h16A (h_n), writes other.
  for (int t = 0; t < 16; ++t){
    const __hip_bfloat16* hin = (t & 1) ? h16B : h16A;
    __hip_bfloat16* hout      = (t & 1) ? h16A : h16B;
    dec_step3<<<256, 256, 0, stream>>>(hin, W16D, gd_d,
                                       dWih + (size_t)128*G, dWih + (size_t)129*G,
                                       yb, fut, cb, dh32, hout, t);
    attn_pred_kernel<<<B, 256, 0, stream>>>(eo16, encWe, dh32, attnW, attnb, outW, outb,
                                            fut, yb, out, t);
  }
}